// Round 1
// baseline (7000.262 us; speedup 1.0000x reference)
//
#include <hip/hip_runtime.h>

#define NN 100000
#define NE 1600000
#define ET 1700000        // NE + NN self-loops
#define NEG 0.2f

// ---------------- workspace layout (bytes) ----------------
#define SRC_OFF   0ULL
#define DST_OFF   6800000ULL
#define H1_OFF    13600000ULL          // 102.4MB ; later reused: h2 at base, h3 at +16MB
#define H2_OFF    H1_OFF
#define H3_OFF    (H1_OFF + 16000000ULL)
#define AGG1_OFF  116000000ULL         // 102.4MB ; later: agg2 at base (->x3), agg3 at +16MB
#define AGG2_OFF  AGG1_OFF
#define AGG3_OFF  (AGG1_OFF + 16000000ULL)
#define AS_OFF    218400000ULL         // 3.2MB slot (layer1 N*8 floats; reused smaller later)
#define AD_OFF    221600000ULL
#define M_OFF     224800000ULL
#define DEN_OFF   228000000ULL
#define WS_NEED   231200000ULL

__device__ __forceinline__ unsigned fenc(float f) {
  unsigned u = __float_as_uint(f);
  return (u & 0x80000000u) ? ~u : (u | 0x80000000u);
}
__device__ __forceinline__ float fdec(unsigned e) {
  return (e & 0x80000000u) ? __uint_as_float(e & 0x7FFFFFFFu) : __uint_as_float(~e);
}
__device__ __forceinline__ float lrelu(float x) { return x > 0.f ? x : NEG * x; }

__global__ __launch_bounds__(256) void k_sentinel(float* out, int n) {
  int i = blockIdx.x * 256 + threadIdx.x;
  if (i < n) out[i] = 12345.0f;
}

// Normalize edge_index (int32 or int64, detected on-device) into int32 src/dst,
// appending self-loops.
__global__ __launch_bounds__(256) void k_prep_edges(const int* __restrict__ raw,
                                                    int* __restrict__ src,
                                                    int* __restrict__ dst) {
  bool is64 = true;
  #pragma unroll
  for (int i = 1; i < 32; i += 2) is64 = is64 && (raw[i] == 0);
  long long e = (long long)blockIdx.x * 256 + threadIdx.x;
  if (e >= ET) return;
  int s, d;
  if (e < NE) {
    if (is64) {
      const long long* r = (const long long*)raw;
      s = (int)r[e];
      d = (int)r[NE + e];
    } else {
      s = raw[e];
      d = raw[NE + e];
    }
  } else {
    s = d = (int)(e - NE);
  }
  src[e] = s;
  dst[e] = d;
}

// h1[N,256] = x[N,128] @ W1[128,256].  8 rows/block, x rows staged in LDS.
__global__ __launch_bounds__(256) void k_gemm1(const float* __restrict__ x,
                                               const float* __restrict__ W,
                                               float* __restrict__ h) {
  __shared__ float xs[8][128];
  const int tid = threadIdx.x;
  const long long n0 = (long long)blockIdx.x * 8;
  {
    int r = tid >> 5, c4 = (tid & 31) << 2;
    *(float4*)&xs[r][c4] = *(const float4*)(x + (n0 + r) * 128 + c4);
  }
  __syncthreads();
  float acc[8] = {};
  const int c = tid;
  #pragma unroll 4
  for (int k = 0; k < 128; k += 4) {
    float w0 = W[(k + 0) * 256 + c];
    float w1 = W[(k + 1) * 256 + c];
    float w2 = W[(k + 2) * 256 + c];
    float w3 = W[(k + 3) * 256 + c];
    #pragma unroll
    for (int n = 0; n < 8; ++n) {
      float4 xv = *(const float4*)&xs[n][k];
      acc[n] += xv.x * w0;
      acc[n] += xv.y * w1;
      acc[n] += xv.z * w2;
      acc[n] += xv.w * w3;
    }
  }
  #pragma unroll
  for (int n = 0; n < 8; ++n) h[(n0 + n) * 256 + c] = acc[n];
}

// a_s[n,h], a_d[n,h] for layer 1 (H=8, C=32).  One block per node.
__global__ __launch_bounds__(256) void k_att1(const float* __restrict__ h,
                                              const float* __restrict__ as,
                                              const float* __restrict__ ad,
                                              float* __restrict__ a_s,
                                              float* __restrict__ a_d) {
  int n = blockIdx.x;
  int tid = threadIdx.x;            // head*32 + c
  float v = h[(long long)n * 256 + tid];
  float p = v * as[tid];
  float q = v * ad[tid];
  #pragma unroll
  for (int off = 16; off; off >>= 1) {
    p += __shfl_down(p, off, 32);
    q += __shfl_down(q, off, 32);
  }
  if ((tid & 31) == 0) {
    int hd = tid >> 5;
    a_s[n * 8 + hd] = p;
    a_d[n * 8 + hd] = q;
  }
}

// a_s/a_d for H=1, C=32 (layer 2): 8 nodes per 256-thread block, shuffle reduce.
__global__ __launch_bounds__(256) void k_att2(const float* __restrict__ h,
                                              const float* __restrict__ as,
                                              const float* __restrict__ ad,
                                              float* __restrict__ a_s,
                                              float* __restrict__ a_d) {
  int n = blockIdx.x * 8 + (threadIdx.x >> 5);
  int c = threadIdx.x & 31;
  float v = h[(long long)n * 32 + c];
  float p = v * as[c];
  float q = v * ad[c];
  #pragma unroll
  for (int off = 16; off; off >>= 1) {
    p += __shfl_down(p, off, 32);
    q += __shfl_down(q, off, 32);
  }
  if (c == 0) { a_s[n] = p; a_d[n] = q; }
}

// a_s/a_d for H=1, C=40 (layer 3): one thread per node.
__global__ __launch_bounds__(256) void k_att3(const float* __restrict__ h,
                                              const float* __restrict__ as,
                                              const float* __restrict__ ad,
                                              float* __restrict__ a_s,
                                              float* __restrict__ a_d) {
  int n = blockIdx.x * 256 + threadIdx.x;
  if (n >= NN) return;
  float p = 0.f, q = 0.f;
  #pragma unroll
  for (int c = 0; c < 40; ++c) {
    float v = h[(long long)n * 40 + c];
    p += v * as[c];
    q += v * ad[c];
  }
  a_s[n] = p;
  a_d[n] = q;
}

template <int H>
__global__ __launch_bounds__(256) void k_edge_max(const int* __restrict__ src,
                                                  const int* __restrict__ dst,
                                                  const float* __restrict__ a_s,
                                                  const float* __restrict__ a_d,
                                                  unsigned* __restrict__ m) {
  long long i = (long long)blockIdx.x * 256 + threadIdx.x;
  if (i >= (long long)ET * H) return;
  long long e = i / H;
  int hd = (int)(i % H);
  int s = src[e], d = dst[e];
  float v = lrelu(a_s[s * H + hd] + a_d[d * H + hd]);
  atomicMax(&m[d * H + hd], fenc(v));
}

template <int H>
__global__ __launch_bounds__(256) void k_edge_sum(const int* __restrict__ src,
                                                  const int* __restrict__ dst,
                                                  const float* __restrict__ a_s,
                                                  const float* __restrict__ a_d,
                                                  const unsigned* __restrict__ m,
                                                  float* __restrict__ den) {
  long long i = (long long)blockIdx.x * 256 + threadIdx.x;
  if (i >= (long long)ET * H) return;
  long long e = i / H;
  int hd = (int)(i % H);
  int s = src[e], d = dst[e];
  float v = lrelu(a_s[s * H + hd] + a_d[d * H + hd]);
  float w = __expf(v - fdec(m[d * H + hd]));
  atomicAdd(&den[d * H + hd], w);
}

// Layer-1 message pass: one wave per edge, lane l covers channels [4l,4l+4).
__global__ __launch_bounds__(256) void k_msg1(const int* __restrict__ src,
                                              const int* __restrict__ dst,
                                              const float* __restrict__ a_s,
                                              const float* __restrict__ a_d,
                                              const unsigned* __restrict__ m,
                                              const float* __restrict__ den,
                                              const float* __restrict__ h,
                                              float* __restrict__ out) {
  long long idx = (long long)blockIdx.x * 256 + threadIdx.x;
  long long e = idx >> 6;
  if (e >= ET) return;
  int l = threadIdx.x & 63;
  int s = src[e], d = dst[e];
  int hd = l >> 3;
  float v = lrelu(a_s[s * 8 + hd] + a_d[d * 8 + hd]);
  float alpha = __expf(v - fdec(m[d * 8 + hd])) / den[d * 8 + hd];
  float4 hv = *(const float4*)(h + (long long)s * 256 + l * 4);
  float* o = out + (long long)d * 256 + l * 4;
  atomicAdd(o + 0, alpha * hv.x);
  atomicAdd(o + 1, alpha * hv.y);
  atomicAdd(o + 2, alpha * hv.z);
  atomicAdd(o + 3, alpha * hv.w);
}

// H=1 message pass, thread per (edge, channel).
template <int C>
__global__ __launch_bounds__(256) void k_msgH1(const int* __restrict__ src,
                                               const int* __restrict__ dst,
                                               const float* __restrict__ a_s,
                                               const float* __restrict__ a_d,
                                               const unsigned* __restrict__ m,
                                               const float* __restrict__ den,
                                               const float* __restrict__ h,
                                               float* __restrict__ out) {
  long long idx = (long long)blockIdx.x * 256 + threadIdx.x;
  if (idx >= (long long)ET * C) return;
  long long e = idx / C;
  int c = (int)(idx % C);
  int s = src[e], d = dst[e];
  float v = lrelu(a_s[s] + a_d[d]);
  float alpha = __expf(v - fdec(m[d])) / den[d];
  atomicAdd(&out[(long long)d * C + c], alpha * h[(long long)s * C + c]);
}

template <int C>
__global__ __launch_bounds__(256) void k_bias_elu(float* __restrict__ x,
                                                  const float* __restrict__ b,
                                                  long long total) {
  long long i = (long long)blockIdx.x * 256 + threadIdx.x;
  long long stride = (long long)gridDim.x * 256;
  for (; i < total; i += stride) {
    float v = x[i] + b[i & (C - 1)];
    x[i] = v > 0.f ? v : expm1f(v);
  }
}

// h2[N,32] = x2[N,256] @ W2[256,32].  32 rows/block staged in LDS.
__global__ __launch_bounds__(256) void k_gemm2(const float* __restrict__ x,
                                               const float* __restrict__ W,
                                               float* __restrict__ h) {
  __shared__ float xs[32][256];
  const int tid = threadIdx.x;
  const long long n0 = (long long)blockIdx.x * 32;
  #pragma unroll
  for (int i = 0; i < 8; ++i) {
    int t = tid + i * 256;          // float4 index 0..2047
    int r = t >> 6;
    int c4 = (t & 63) << 2;
    *(float4*)&xs[r][c4] = *(const float4*)(x + (n0 + r) * 256 + c4);
  }
  __syncthreads();
  const int c = tid & 31;
  const int r0 = tid >> 5;          // 0..7
  float acc[4] = {};
  for (int k = 0; k < 256; k += 4) {
    #pragma unroll
    for (int kk = 0; kk < 4; ++kk) {
      float w = W[(k + kk) * 32 + c];
      #pragma unroll
      for (int j = 0; j < 4; ++j) acc[j] += xs[r0 + j * 8][k + kk] * w;
    }
  }
  #pragma unroll
  for (int j = 0; j < 4; ++j) h[(n0 + r0 + j * 8) * 32 + c] = acc[j];
}

// h3[N,40] = x3[N,32] @ W3[32,40].  8 rows/block, W3 in LDS. 320 threads.
__global__ __launch_bounds__(320) void k_gemm3(const float* __restrict__ x,
                                               const float* __restrict__ W,
                                               float* __restrict__ h) {
  __shared__ float xs[8][32];
  __shared__ float Ws[32 * 40];
  const int tid = threadIdx.x;
  const long long n0 = (long long)blockIdx.x * 8;
  if (tid < 256) {
    int r = tid >> 5, c = tid & 31;
    xs[r][c] = x[(n0 + r) * 32 + c];
  }
  for (int i = tid; i < 32 * 40; i += 320) Ws[i] = W[i];
  __syncthreads();
  const int r = tid / 40, c = tid % 40;
  float acc = 0.f;
  #pragma unroll
  for (int k = 0; k < 32; ++k) acc += xs[r][k] * Ws[k * 40 + c];
  h[(n0 + r) * 40 + c] = acc;
}

__global__ __launch_bounds__(256) void k_logsoftmax(const float* __restrict__ agg,
                                                    const float* __restrict__ b,
                                                    float* __restrict__ out) {
  int n = blockIdx.x * 256 + threadIdx.x;
  if (n >= NN) return;
  float v[40];
  float mx = -3.4e38f;
  #pragma unroll
  for (int c = 0; c < 40; ++c) {
    v[c] = agg[(long long)n * 40 + c] + b[c];
    mx = fmaxf(mx, v[c]);
  }
  float s = 0.f;
  #pragma unroll
  for (int c = 0; c < 40; ++c) s += __expf(v[c] - mx);
  float lse = mx + __logf(s);
  #pragma unroll
  for (int c = 0; c < 40; ++c) out[(long long)n * 40 + c] = v[c] - lse;
}

extern "C" void kernel_launch(void* const* d_in, const int* in_sizes, int n_in,
                              void* d_out, int out_size, void* d_ws, size_t ws_size,
                              hipStream_t stream) {
  const float* x   = (const float*)d_in[0];
  const int*   eix = (const int*)d_in[1];
  const float* W1  = (const float*)d_in[2];
  const float* as1 = (const float*)d_in[3];
  const float* ad1 = (const float*)d_in[4];
  const float* b1  = (const float*)d_in[5];
  const float* W2  = (const float*)d_in[6];
  const float* as2 = (const float*)d_in[7];
  const float* ad2 = (const float*)d_in[8];
  const float* b2  = (const float*)d_in[9];
  const float* W3  = (const float*)d_in[10];
  const float* as3 = (const float*)d_in[11];
  const float* ad3 = (const float*)d_in[12];
  const float* b3  = (const float*)d_in[13];
  float* out = (float*)d_out;

  if (ws_size < WS_NEED) {   // unambiguous failure signature if ws is too small
    k_sentinel<<<(out_size + 255) / 256, 256, 0, stream>>>(out, out_size);
    return;
  }

  char* ws = (char*)d_ws;
  int*      src  = (int*)(ws + SRC_OFF);
  int*      dst  = (int*)(ws + DST_OFF);
  float*    h1   = (float*)(ws + H1_OFF);
  float*    h2   = (float*)(ws + H2_OFF);
  float*    h3   = (float*)(ws + H3_OFF);
  float*    agg1 = (float*)(ws + AGG1_OFF);
  float*    agg2 = (float*)(ws + AGG2_OFF);
  float*    agg3 = (float*)(ws + AGG3_OFF);
  float*    aS   = (float*)(ws + AS_OFF);
  float*    aD   = (float*)(ws + AD_OFF);
  unsigned* mbuf = (unsigned*)(ws + M_OFF);
  float*    den  = (float*)(ws + DEN_OFF);

  // ---- edges ----
  k_prep_edges<<<(ET + 255) / 256, 256, 0, stream>>>(eix, src, dst);

  // ---- layer 1: 128 -> 8x32 concat ----
  k_gemm1<<<NN / 8, 256, 0, stream>>>(x, W1, h1);
  k_att1<<<NN, 256, 0, stream>>>(h1, as1, ad1, aS, aD);
  hipMemsetAsync(ws + M_OFF, 0, 6400000, stream);           // m (enc 0 < any real) + den
  hipMemsetAsync(ws + AGG1_OFF, 0, 102400000, stream);
  k_edge_max<8><<<(ET * 8) / 256, 256, 0, stream>>>(src, dst, aS, aD, mbuf);
  k_edge_sum<8><<<(ET * 8) / 256, 256, 0, stream>>>(src, dst, aS, aD, mbuf, den);
  k_msg1<<<(ET * 64) / 256, 256, 0, stream>>>(src, dst, aS, aD, mbuf, den, h1, agg1);
  k_bias_elu<256><<<4096, 256, 0, stream>>>(agg1, b1, (long long)NN * 256);

  // ---- layer 2: 256 -> 32 ----
  k_gemm2<<<NN / 32, 256, 0, stream>>>(agg1, W2, h2);
  k_att2<<<NN / 8, 256, 0, stream>>>(h2, as2, ad2, aS, aD);
  hipMemsetAsync(ws + M_OFF, 0, 6400000, stream);
  hipMemsetAsync(ws + AGG2_OFF, 0, 12800000, stream);
  k_edge_max<1><<<(ET + 255) / 256, 256, 0, stream>>>(src, dst, aS, aD, mbuf);
  k_edge_sum<1><<<(ET + 255) / 256, 256, 0, stream>>>(src, dst, aS, aD, mbuf, den);
  k_msgH1<32><<<(ET * 32) / 256, 256, 0, stream>>>(src, dst, aS, aD, mbuf, den, h2, agg2);
  k_bias_elu<32><<<4096, 256, 0, stream>>>(agg2, b2, (long long)NN * 32);

  // ---- layer 3: 32 -> 40 ----
  k_gemm3<<<NN / 8, 320, 0, stream>>>(agg2, W3, h3);
  k_att3<<<(NN + 255) / 256, 256, 0, stream>>>(h3, as3, ad3, aS, aD);
  hipMemsetAsync(ws + M_OFF, 0, 6400000, stream);
  hipMemsetAsync(ws + AGG3_OFF, 0, 16000000, stream);
  k_edge_max<1><<<(ET + 255) / 256, 256, 0, stream>>>(src, dst, aS, aD, mbuf);
  k_edge_sum<1><<<(ET + 255) / 256, 256, 0, stream>>>(src, dst, aS, aD, mbuf, den);
  k_msgH1<40><<<(ET * 40) / 256, 256, 0, stream>>>(src, dst, aS, aD, mbuf, den, h3, agg3);

  // ---- log_softmax ----
  k_logsoftmax<<<(NN + 255) / 256, 256, 0, stream>>>(agg3, b3, out);
}

// Round 2
// 1113.213 us; speedup vs baseline: 6.2883x; 6.2883x over previous
//
#include <hip/hip_runtime.h>

#define NN 100000
#define NE 1600000
#define ET 1700000        // NE + NN self-loops
#define NEG 0.2f
#define FNEG 3.4e38f

// ---------------- workspace layout (bytes) ----------------
#define SRC_OFF   0ULL
#define DST_OFF   6800000ULL
#define RP_OFF    13600000ULL         // rowptr: (NN+1)*4
#define CNT_OFF   14000128ULL         // deg/fill cursor: NN*4
#define CSR_OFF   14400128ULL         // csr src ids: ET*4
#define H_OFF     21200128ULL         // h1 (N*256*4 = 102.4MB); reused for h2,h3
#define AGG_OFF   123600128ULL        // agg1 (102.4MB); reused for agg2
#define AS_OFF    SRC_OFF             // aS aliases src (dead after CSR fill)
#define AD_OFF    DST_OFF             // aD aliases dst
#define WS_NEED   226000128ULL

__device__ __forceinline__ float lrelu(float x) { return x > 0.f ? x : NEG * x; }

__global__ __launch_bounds__(256) void k_sentinel(float* out, int n) {
  int i = blockIdx.x * 256 + threadIdx.x;
  if (i < n) out[i] = 12345.0f;
}

// Normalize edge_index (int32 or int64, detected on-device) into int32 src/dst,
// appending self-loops.
__global__ __launch_bounds__(256) void k_prep_edges(const int* __restrict__ raw,
                                                    int* __restrict__ src,
                                                    int* __restrict__ dst) {
  bool is64 = true;
  #pragma unroll
  for (int i = 1; i < 32; i += 2) is64 = is64 && (raw[i] == 0);
  long long e = (long long)blockIdx.x * 256 + threadIdx.x;
  if (e >= ET) return;
  int s, d;
  if (e < NE) {
    if (is64) {
      const long long* r = (const long long*)raw;
      s = (int)r[e];
      d = (int)r[NE + e];
    } else {
      s = raw[e];
      d = raw[NE + e];
    }
  } else {
    s = d = (int)(e - NE);
  }
  src[e] = s;
  dst[e] = d;
}

__global__ __launch_bounds__(256) void k_deg(const int* __restrict__ dst,
                                             int* __restrict__ deg) {
  long long e = (long long)blockIdx.x * 256 + threadIdx.x;
  if (e >= ET) return;
  atomicAdd(&deg[dst[e]], 1);
}

// Single-block exclusive scan of deg[NN] -> rowptr[NN+1] (wave-shuffle based).
__global__ __launch_bounds__(1024) void k_scan(const int* __restrict__ deg,
                                               int* __restrict__ rowptr) {
  __shared__ int wsum[16];
  __shared__ int carry_s;
  const int lane = threadIdx.x & 63;
  const int wid = threadIdx.x >> 6;
  if (threadIdx.x == 0) carry_s = 0;
  __syncthreads();
  for (int base = 0; base < NN; base += 1024) {
    int i = base + threadIdx.x;
    int x = (i < NN) ? deg[i] : 0;
    #pragma unroll
    for (int off = 1; off < 64; off <<= 1) {
      int t = __shfl_up(x, off);
      if (lane >= off) x += t;
    }
    if (lane == 63) wsum[wid] = x;
    int carry = carry_s;             // previous iteration's value
    __syncthreads();
    if (wid == 0) {
      int w = (lane < 16) ? wsum[lane] : 0;
      #pragma unroll
      for (int off = 1; off < 16; off <<= 1) {
        int t = __shfl_up(w, off);
        if (lane >= off) w += t;
      }
      if (lane < 16) wsum[lane] = w;
      if (lane == 15) carry_s = carry + w;
    }
    __syncthreads();
    int wpre = (wid == 0) ? 0 : wsum[wid - 1];
    if (i < NN) rowptr[i + 1] = carry + wpre + x;
    __syncthreads();
  }
  if (threadIdx.x == 0) rowptr[0] = 0;
}

__global__ __launch_bounds__(256) void k_fill(const int* __restrict__ src,
                                              const int* __restrict__ dst,
                                              const int* __restrict__ rowptr,
                                              int* __restrict__ cnt,
                                              int* __restrict__ csr) {
  long long e = (long long)blockIdx.x * 256 + threadIdx.x;
  if (e >= ET) return;
  int d = dst[e];
  int p = atomicAdd(&cnt[d], 1);
  csr[rowptr[d] + p] = src[e];
}

// h1[N,256] = x[N,128] @ W1[128,256].  8 rows/block, x rows staged in LDS.
__global__ __launch_bounds__(256) void k_gemm1(const float* __restrict__ x,
                                               const float* __restrict__ W,
                                               float* __restrict__ h) {
  __shared__ float xs[8][128];
  const int tid = threadIdx.x;
  const long long n0 = (long long)blockIdx.x * 8;
  {
    int r = tid >> 5, c4 = (tid & 31) << 2;
    *(float4*)&xs[r][c4] = *(const float4*)(x + (n0 + r) * 128 + c4);
  }
  __syncthreads();
  float acc[8] = {};
  const int c = tid;
  #pragma unroll 4
  for (int k = 0; k < 128; k += 4) {
    float w0 = W[(k + 0) * 256 + c];
    float w1 = W[(k + 1) * 256 + c];
    float w2 = W[(k + 2) * 256 + c];
    float w3 = W[(k + 3) * 256 + c];
    #pragma unroll
    for (int n = 0; n < 8; ++n) {
      float4 xv = *(const float4*)&xs[n][k];
      acc[n] += xv.x * w0;
      acc[n] += xv.y * w1;
      acc[n] += xv.z * w2;
      acc[n] += xv.w * w3;
    }
  }
  #pragma unroll
  for (int n = 0; n < 8; ++n) h[(n0 + n) * 256 + c] = acc[n];
}

// a_s[n,h], a_d[n,h] for layer 1 (H=8, C=32).  One block per node.
__global__ __launch_bounds__(256) void k_att1(const float* __restrict__ h,
                                              const float* __restrict__ as,
                                              const float* __restrict__ ad,
                                              float* __restrict__ a_s,
                                              float* __restrict__ a_d) {
  int n = blockIdx.x;
  int tid = threadIdx.x;            // head*32 + c
  float v = h[(long long)n * 256 + tid];
  float p = v * as[tid];
  float q = v * ad[tid];
  #pragma unroll
  for (int off = 16; off; off >>= 1) {
    p += __shfl_down(p, off, 32);
    q += __shfl_down(q, off, 32);
  }
  if ((tid & 31) == 0) {
    int hd = tid >> 5;
    a_s[n * 8 + hd] = p;
    a_d[n * 8 + hd] = q;
  }
}

// a_s/a_d for H=1, C=32 (layer 2): 8 nodes per 256-thread block, shuffle reduce.
__global__ __launch_bounds__(256) void k_att2(const float* __restrict__ h,
                                              const float* __restrict__ as,
                                              const float* __restrict__ ad,
                                              float* __restrict__ a_s,
                                              float* __restrict__ a_d) {
  int n = blockIdx.x * 8 + (threadIdx.x >> 5);
  int c = threadIdx.x & 31;
  float v = h[(long long)n * 32 + c];
  float p = v * as[c];
  float q = v * ad[c];
  #pragma unroll
  for (int off = 16; off; off >>= 1) {
    p += __shfl_down(p, off, 32);
    q += __shfl_down(q, off, 32);
  }
  if (c == 0) { a_s[n] = p; a_d[n] = q; }
}

// a_s/a_d for H=1, C=40 (layer 3): one thread per node.
__global__ __launch_bounds__(256) void k_att3(const float* __restrict__ h,
                                              const float* __restrict__ as,
                                              const float* __restrict__ ad,
                                              float* __restrict__ a_s,
                                              float* __restrict__ a_d) {
  int n = blockIdx.x * 256 + threadIdx.x;
  if (n >= NN) return;
  float p = 0.f, q = 0.f;
  #pragma unroll
  for (int c = 0; c < 40; ++c) {
    float v = h[(long long)n * 40 + c];
    p += v * as[c];
    q += v * ad[c];
  }
  a_s[n] = p;
  a_d[n] = q;
}

// Layer-1 softmax+aggregate+bias+ELU.  One wave per node (4 nodes/block).
// Pass 1: 8 edge-groups x 8 heads online max/sum -> butterfly merge.
// Pass 2: lane l accumulates channels [4l,4l+4) over incoming edges.
__global__ __launch_bounds__(256) void k_agg1(const int* __restrict__ rowptr,
                                              const int* __restrict__ csr,
                                              const float* __restrict__ a_s,
                                              const float* __restrict__ a_d,
                                              const float* __restrict__ h,
                                              const float* __restrict__ b,
                                              float* __restrict__ out) {
  const int node = blockIdx.x * 4 + (threadIdx.x >> 6);
  const int lane = threadIdx.x & 63;
  const int beg = rowptr[node], end = rowptr[node + 1];

  // ---- pass 1: per-head online (max, sum) ----
  const int hd = lane & 7;
  const int eg = lane >> 3;
  const float adv = a_d[node * 8 + hd];
  float mx = -FNEG, sm = 0.f;
  for (int i = beg + eg; i < end; i += 8) {
    int s = csr[i];
    float v = lrelu(a_s[s * 8 + hd] + adv);
    float nm = fmaxf(mx, v);
    sm = sm * __expf(mx - nm) + __expf(v - nm);
    mx = nm;
  }
  #pragma unroll
  for (int off = 8; off < 64; off <<= 1) {
    float mo = __shfl_xor(mx, off);
    float so = __shfl_xor(sm, off);
    float nm = fmaxf(mx, mo);
    sm = sm * __expf(mx - nm) + so * __expf(mo - nm);
    mx = nm;
  }
  // lane j holds (mx,sm) for head j&7; lane l needs head l>>3 -> source lane l>>3
  const int hd2 = lane >> 3;
  float m2 = __shfl(mx, hd2);
  float rden = 1.0f / __shfl(sm, hd2);
  const float adv2 = a_d[node * 8 + hd2];

  // ---- pass 2: gather + weighted accumulate ----
  float4 acc = {0.f, 0.f, 0.f, 0.f};
  for (int i = beg; i < end; ++i) {
    int s = csr[i];
    float v = lrelu(a_s[s * 8 + hd2] + adv2);
    float alpha = __expf(v - m2) * rden;
    float4 hv = *(const float4*)(h + (long long)s * 256 + lane * 4);
    acc.x += alpha * hv.x;
    acc.y += alpha * hv.y;
    acc.z += alpha * hv.z;
    acc.w += alpha * hv.w;
  }
  // bias + ELU
  float4 bv = *(const float4*)(b + lane * 4);
  acc.x += bv.x; acc.y += bv.y; acc.z += bv.z; acc.w += bv.w;
  acc.x = acc.x > 0.f ? acc.x : expm1f(acc.x);
  acc.y = acc.y > 0.f ? acc.y : expm1f(acc.y);
  acc.z = acc.z > 0.f ? acc.z : expm1f(acc.z);
  acc.w = acc.w > 0.f ? acc.w : expm1f(acc.w);
  *(float4*)(out + (long long)node * 256 + lane * 4) = acc;
}

// Layer-2 softmax+aggregate+bias+ELU. H=1, C=32. Half-wave per node.
__global__ __launch_bounds__(256) void k_agg2(const int* __restrict__ rowptr,
                                              const int* __restrict__ csr,
                                              const float* __restrict__ a_s,
                                              const float* __restrict__ a_d,
                                              const float* __restrict__ h,
                                              const float* __restrict__ b,
                                              float* __restrict__ out) {
  const int node = blockIdx.x * 8 + (threadIdx.x >> 5);
  const int lane = threadIdx.x & 31;
  const int beg = rowptr[node], end = rowptr[node + 1];
  const float adv = a_d[node];

  float mx = -FNEG, sm = 0.f;
  for (int i = beg + lane; i < end; i += 32) {
    float v = lrelu(a_s[csr[i]] + adv);
    float nm = fmaxf(mx, v);
    sm = sm * __expf(mx - nm) + __expf(v - nm);
    mx = nm;
  }
  #pragma unroll
  for (int off = 1; off < 32; off <<= 1) {
    float mo = __shfl_xor(mx, off, 32);
    float so = __shfl_xor(sm, off, 32);
    float nm = fmaxf(mx, mo);
    sm = sm * __expf(mx - nm) + so * __expf(mo - nm);
    mx = nm;
  }
  float rden = 1.0f / sm;

  float acc = 0.f;
  for (int i = beg; i < end; ++i) {
    int s = csr[i];
    float alpha = __expf(lrelu(a_s[s] + adv) - mx) * rden;
    acc += alpha * h[(long long)s * 32 + lane];
  }
  acc += b[lane];
  out[(long long)node * 32 + lane] = acc > 0.f ? acc : expm1f(acc);
}

// Layer-3 softmax+aggregate + bias + log_softmax -> final out. H=1, C=40.
// One wave per node.
__global__ __launch_bounds__(256) void k_agg3(const int* __restrict__ rowptr,
                                              const int* __restrict__ csr,
                                              const float* __restrict__ a_s,
                                              const float* __restrict__ a_d,
                                              const float* __restrict__ h,
                                              const float* __restrict__ b,
                                              float* __restrict__ out) {
  const int node = blockIdx.x * 4 + (threadIdx.x >> 6);
  const int lane = threadIdx.x & 63;
  const int beg = rowptr[node], end = rowptr[node + 1];
  const float adv = a_d[node];

  float mx = -FNEG, sm = 0.f;
  for (int i = beg + lane; i < end; i += 64) {
    float v = lrelu(a_s[csr[i]] + adv);
    float nm = fmaxf(mx, v);
    sm = sm * __expf(mx - nm) + __expf(v - nm);
    mx = nm;
  }
  #pragma unroll
  for (int off = 1; off < 64; off <<= 1) {
    float mo = __shfl_xor(mx, off);
    float so = __shfl_xor(sm, off);
    float nm = fmaxf(mx, mo);
    sm = sm * __expf(mx - nm) + so * __expf(mo - nm);
    mx = nm;
  }
  float rden = 1.0f / sm;

  float acc = 0.f;
  for (int i = beg; i < end; ++i) {
    int s = csr[i];
    float alpha = __expf(lrelu(a_s[s] + adv) - mx) * rden;
    if (lane < 40) acc += alpha * h[(long long)s * 40 + lane];
  }
  // bias + log_softmax over 40 channels
  float v = (lane < 40) ? acc + b[lane] : -FNEG;
  float vmax = v;
  #pragma unroll
  for (int off = 1; off < 64; off <<= 1) vmax = fmaxf(vmax, __shfl_xor(vmax, off));
  float ex = (lane < 40) ? __expf(v - vmax) : 0.f;
  float es = ex;
  #pragma unroll
  for (int off = 1; off < 64; off <<= 1) es += __shfl_xor(es, off);
  float lse = vmax + __logf(es);
  if (lane < 40) out[(long long)node * 40 + lane] = v - lse;
}

// h2[N,32] = x2[N,256] @ W2[256,32].  32 rows/block staged in LDS.
__global__ __launch_bounds__(256) void k_gemm2(const float* __restrict__ x,
                                               const float* __restrict__ W,
                                               float* __restrict__ h) {
  __shared__ float xs[32][256];
  const int tid = threadIdx.x;
  const long long n0 = (long long)blockIdx.x * 32;
  #pragma unroll
  for (int i = 0; i < 8; ++i) {
    int t = tid + i * 256;          // float4 index 0..2047
    int r = t >> 6;
    int c4 = (t & 63) << 2;
    *(float4*)&xs[r][c4] = *(const float4*)(x + (n0 + r) * 256 + c4);
  }
  __syncthreads();
  const int c = tid & 31;
  const int r0 = tid >> 5;          // 0..7
  float acc[4] = {};
  for (int k = 0; k < 256; k += 4) {
    #pragma unroll
    for (int kk = 0; kk < 4; ++kk) {
      float w = W[(k + kk) * 32 + c];
      #pragma unroll
      for (int j = 0; j < 4; ++j) acc[j] += xs[r0 + j * 8][k + kk] * w;
    }
  }
  #pragma unroll
  for (int j = 0; j < 4; ++j) h[(n0 + r0 + j * 8) * 32 + c] = acc[j];
}

// h3[N,40] = x3[N,32] @ W3[32,40].  8 rows/block, W3 in LDS. 320 threads.
__global__ __launch_bounds__(320) void k_gemm3(const float* __restrict__ x,
                                               const float* __restrict__ W,
                                               float* __restrict__ h) {
  __shared__ float xs[8][32];
  __shared__ float Ws[32 * 40];
  const int tid = threadIdx.x;
  const long long n0 = (long long)blockIdx.x * 8;
  if (tid < 256) {
    int r = tid >> 5, c = tid & 31;
    xs[r][c] = x[(n0 + r) * 32 + c];
  }
  for (int i = tid; i < 32 * 40; i += 320) Ws[i] = W[i];
  __syncthreads();
  const int r = tid / 40, c = tid % 40;
  float acc = 0.f;
  #pragma unroll
  for (int k = 0; k < 32; ++k) acc += xs[r][k] * Ws[k * 40 + c];
  h[(n0 + r) * 40 + c] = acc;
}

extern "C" void kernel_launch(void* const* d_in, const int* in_sizes, int n_in,
                              void* d_out, int out_size, void* d_ws, size_t ws_size,
                              hipStream_t stream) {
  const float* x   = (const float*)d_in[0];
  const int*   eix = (const int*)d_in[1];
  const float* W1  = (const float*)d_in[2];
  const float* as1 = (const float*)d_in[3];
  const float* ad1 = (const float*)d_in[4];
  const float* b1  = (const float*)d_in[5];
  const float* W2  = (const float*)d_in[6];
  const float* as2 = (const float*)d_in[7];
  const float* ad2 = (const float*)d_in[8];
  const float* b2  = (const float*)d_in[9];
  const float* W3  = (const float*)d_in[10];
  const float* as3 = (const float*)d_in[11];
  const float* ad3 = (const float*)d_in[12];
  const float* b3  = (const float*)d_in[13];
  float* out = (float*)d_out;

  if (ws_size < WS_NEED) {   // unambiguous failure signature if ws is too small
    k_sentinel<<<(out_size + 255) / 256, 256, 0, stream>>>(out, out_size);
    return;
  }

  char* ws = (char*)d_ws;
  int*   src    = (int*)(ws + SRC_OFF);
  int*   dst    = (int*)(ws + DST_OFF);
  int*   rowptr = (int*)(ws + RP_OFF);
  int*   cnt    = (int*)(ws + CNT_OFF);
  int*   csr    = (int*)(ws + CSR_OFF);
  float* h1     = (float*)(ws + H_OFF);
  float* h2     = (float*)(ws + H_OFF);
  float* h3     = (float*)(ws + H_OFF);
  float* agg1   = (float*)(ws + AGG_OFF);
  float* agg2   = (float*)(ws + AGG_OFF);
  float* aS     = (float*)(ws + AS_OFF);   // aliases src (dead after k_fill)
  float* aD     = (float*)(ws + AD_OFF);   // aliases dst

  // ---- CSR build (once) ----
  k_prep_edges<<<(ET + 255) / 256, 256, 0, stream>>>(eix, src, dst);
  hipMemsetAsync(ws + CNT_OFF, 0, 400000, stream);
  k_deg<<<(ET + 255) / 256, 256, 0, stream>>>(dst, cnt);
  k_scan<<<1, 1024, 0, stream>>>(cnt, rowptr);
  hipMemsetAsync(ws + CNT_OFF, 0, 400000, stream);
  k_fill<<<(ET + 255) / 256, 256, 0, stream>>>(src, dst, rowptr, cnt, csr);

  // ---- layer 1: 128 -> 8x32 concat ----
  k_gemm1<<<NN / 8, 256, 0, stream>>>(x, W1, h1);
  k_att1<<<NN, 256, 0, stream>>>(h1, as1, ad1, aS, aD);   // overwrites src/dst (dead)
  k_agg1<<<NN / 4, 256, 0, stream>>>(rowptr, csr, aS, aD, h1, b1, agg1);

  // ---- layer 2: 256 -> 32 ----
  k_gemm2<<<NN / 32, 256, 0, stream>>>(agg1, W2, h2);     // h2 over h1 (dead)
  k_att2<<<NN / 8, 256, 0, stream>>>(h2, as2, ad2, aS, aD);
  k_agg2<<<NN / 8, 256, 0, stream>>>(rowptr, csr, aS, aD, h2, b2, agg2);  // over agg1 (dead)

  // ---- layer 3: 32 -> 40 ----
  k_gemm3<<<NN / 8, 320, 0, stream>>>(agg2, W3, h3);      // h3 over h2 (dead)
  k_att3<<<(NN + 255) / 256, 256, 0, stream>>>(h3, as3, ad3, aS, aD);
  k_agg3<<<NN / 4, 256, 0, stream>>>(rowptr, csr, aS, aD, h3, b3, out);   // fused log_softmax
}

// Round 4
// 816.463 us; speedup vs baseline: 8.5739x; 1.3635x over previous
//
#include <hip/hip_runtime.h>

#define NN 100000
#define NE 1600000
#define ET 1700000        // NE + NN self-loops
#define NEG 0.2f
#define FNEG 3.4e38f
#define NBSC 98           // scan blocks: ceil(NN/1024)

// ---------------- workspace layout (bytes) ----------------
#define SRC_OFF   0ULL
#define DST_OFF   6800000ULL
#define RP_OFF    13600000ULL         // rowptr (NN+1)*4
#define CNT_OFF   14000128ULL         // deg / fill cursor NN*4
#define CSR_OFF   14400128ULL         // ET*4
#define W1F_OFF   21200128ULL         // 65536  (16mf x 4kk x 64lane x 8 bf16)
#define W2F_OFF   21265664ULL         // 16384  (2mf x 8kk x 64 x 8)
#define W3F_OFF   21282048ULL         // 3072   (3mf x 1kk x 64 x 8)
#define SC_OFF    21285120ULL         // 1024 (block sums)
#define H_OFF     21286144ULL         // h1b 51.2MB (bf16); reused h2b/h3b
#define AGG_OFF   72486144ULL         // agg1b 51.2MB (bf16); reused agg2b
#define WS_NEED   123686144ULL
#define AS_OFF    SRC_OFF             // aS aliases src (dead after k_fill)
#define AD_OFF    DST_OFF

typedef short bf16x8 __attribute__((ext_vector_type(8)));
typedef float f32x4 __attribute__((ext_vector_type(4)));

__device__ __forceinline__ float lrelu(float x) { return x > 0.f ? x : NEG * x; }
__device__ __forceinline__ float b2f(unsigned short u) {
  return __uint_as_float(((unsigned)u) << 16);
}
__device__ __forceinline__ unsigned short f2bu(float f) {   // RNE f32->bf16
  unsigned u = __float_as_uint(f);
  return (unsigned short)((u + 0x7FFFu + ((u >> 16) & 1u)) >> 16);
}

__global__ __launch_bounds__(256) void k_sentinel(float* out, int n) {
  int i = blockIdx.x * 256 + threadIdx.x;
  if (i < n) out[i] = 12345.0f;
}

// Normalize edge_index (int32/int64 auto-detected) into int32 src/dst with
// self-loops appended; fused in-degree count.
__global__ __launch_bounds__(256) void k_prep_edges(const int* __restrict__ raw,
                                                    int* __restrict__ src,
                                                    int* __restrict__ dst,
                                                    int* __restrict__ deg) {
  bool is64 = true;
  #pragma unroll
  for (int i = 1; i < 32; i += 2) is64 = is64 && (raw[i] == 0);
  long long e = (long long)blockIdx.x * 256 + threadIdx.x;
  if (e >= ET) return;
  int s, d;
  if (e < NE) {
    if (is64) {
      const long long* r = (const long long*)raw;
      s = (int)r[e];
      d = (int)r[NE + e];
    } else {
      s = raw[e];
      d = raw[NE + e];
    }
  } else {
    s = d = (int)(e - NE);
  }
  src[e] = s;
  dst[e] = d;
  atomicAdd(&deg[d], 1);
}

// Block-level inclusive scan; rowptr[i+1] = block-local inclusive, bsum[b]=total.
__global__ __launch_bounds__(1024) void k_scan_a(const int* __restrict__ deg,
                                                 int* __restrict__ rowptr,
                                                 int* __restrict__ bsum) {
  __shared__ int wsum[16];
  const int lane = threadIdx.x & 63, wid = threadIdx.x >> 6;
  int i = blockIdx.x * 1024 + threadIdx.x;
  int x = (i < NN) ? deg[i] : 0;
  int inc = x;
  #pragma unroll
  for (int off = 1; off < 64; off <<= 1) {
    int t = __shfl_up(inc, off);
    if (lane >= off) inc += t;
  }
  if (lane == 63) wsum[wid] = inc;
  __syncthreads();
  if (wid == 0) {
    int w = (lane < 16) ? wsum[lane] : 0;
    #pragma unroll
    for (int off = 1; off < 16; off <<= 1) {
      int t = __shfl_up(w, off);
      if (lane >= off) w += t;
    }
    if (lane < 16) wsum[lane] = w;
  }
  __syncthreads();
  int base = wid ? wsum[wid - 1] : 0;
  if (i < NN) rowptr[i + 1] = base + inc;
  if (threadIdx.x == 1023) bsum[blockIdx.x] = base + inc;
}

// Exclusive scan of NBSC block sums (in place).
__global__ __launch_bounds__(128) void k_scan_b(int* __restrict__ bsum) {
  __shared__ int w0tot;
  int tid = threadIdx.x;
  int v = (tid < NBSC) ? bsum[tid] : 0;
  int inc = v;
  #pragma unroll
  for (int off = 1; off < 64; off <<= 1) {
    int t = __shfl_up(inc, off);
    if ((tid & 63) >= off) inc += t;
  }
  if (tid == 63) w0tot = inc;
  __syncthreads();
  if (tid >= 64) inc += w0tot;
  if (tid < NBSC) bsum[tid] = inc - v;
}

__global__ __launch_bounds__(1024) void k_scan_c(int* __restrict__ rowptr,
                                                 const int* __restrict__ bsum) {
  int i = blockIdx.x * 1024 + threadIdx.x;
  if (i < NN) rowptr[i + 1] += bsum[blockIdx.x];
  if (i == 0) rowptr[0] = 0;
}

__global__ __launch_bounds__(256) void k_fill(const int* __restrict__ src,
                                              const int* __restrict__ dst,
                                              const int* __restrict__ rowptr,
                                              int* __restrict__ cnt,
                                              int* __restrict__ csr) {
  long long e = (long long)blockIdx.x * 256 + threadIdx.x;
  if (e >= ET) return;
  int d = dst[e];
  int p = atomicAdd(&cnt[d], 1);
  csr[rowptr[d] + p] = src[e];
}

// Pre-arrange W1/W2/W3 (f32) into MFMA A-fragment order as bf16.
// A-frag convention: row(channel) = lane&15, k = (lane>>4)*8 + j.
__global__ __launch_bounds__(256) void k_prep_w(const float* __restrict__ W1,
                                                const float* __restrict__ W2,
                                                const float* __restrict__ W3,
                                                unsigned short* __restrict__ W1f,
                                                unsigned short* __restrict__ W2f,
                                                unsigned short* __restrict__ W3f) {
  int idx = blockIdx.x * 256 + threadIdx.x;
  if (idx < 4096) {                       // W1: 16 mf x 4 kk
    int fg = idx >> 6, lane = idx & 63;
    int mf = fg >> 2, kk = fg & 3;
    int c = mf * 16 + (lane & 15), k0 = kk * 32 + (lane >> 4) * 8;
    unsigned short* o = W1f + idx * 8;
    #pragma unroll
    for (int j = 0; j < 8; ++j) o[j] = f2bu(W1[(k0 + j) * 256 + c]);
  } else if (idx < 5120) {                // W2: 2 mf x 8 kk
    int t = idx - 4096;
    int fg = t >> 6, lane = t & 63;
    int mf = fg >> 3, kk = fg & 7;
    int c = mf * 16 + (lane & 15), k0 = kk * 32 + (lane >> 4) * 8;
    unsigned short* o = W2f + t * 8;
    #pragma unroll
    for (int j = 0; j < 8; ++j) o[j] = f2bu(W2[(k0 + j) * 32 + c]);
  } else if (idx < 5312) {                // W3: 3 mf x 1 kk (pad ch>=40 with 0)
    int t = idx - 5120;
    int mf = t >> 6, lane = t & 63;
    int c = mf * 16 + (lane & 15), k0 = (lane >> 4) * 8;
    unsigned short* o = W3f + t * 8;
    #pragma unroll
    for (int j = 0; j < 8; ++j) o[j] = (c < 40) ? f2bu(W3[(k0 + j) * 40 + c]) : 0;
  }
}

// h1b[N,256](bf16) = x[N,128] @ W1.  MFMA, channels-as-M, nodes-as-N.
// 64 nodes/block (4 waves x 16), K=128 (4 mfma k-steps), 16 channel-frags.
__global__ __launch_bounds__(256) void k_gemm1(const float* __restrict__ x,
                                               const bf16x8* __restrict__ W1f,
                                               unsigned short* __restrict__ h) {
  __shared__ __align__(16) unsigned short xs[64 * 128];
  const int tid = threadIdx.x;
  const int n0 = blockIdx.x * 64;
  for (int j = tid; j < 2048; j += 256) {       // stage x -> bf16 LDS
    int r = j >> 5;
    int c4 = (j & 31) << 2;
    long long row = n0 + r; if (row >= NN) row = NN - 1;
    float4 v = *(const float4*)(x + row * 128 + c4);
    unsigned short* p = &xs[r * 128 + c4];
    p[0] = f2bu(v.x); p[1] = f2bu(v.y); p[2] = f2bu(v.z); p[3] = f2bu(v.w);
  }
  __syncthreads();
  const int w = tid >> 6, lane = tid & 63;
  const int nloc = w * 16 + (lane & 15);
  const int node = n0 + nloc;
  bf16x8 bfr[4];
  #pragma unroll
  for (int kk = 0; kk < 4; ++kk)
    bfr[kk] = *(const bf16x8*)&xs[nloc * 128 + kk * 32 + (lane >> 4) * 8];
  const int ch_base = (lane >> 4) * 4;
  #pragma unroll
  for (int mf = 0; mf < 16; ++mf) {
    f32x4 acc = {0.f, 0.f, 0.f, 0.f};
    #pragma unroll
    for (int kk = 0; kk < 4; ++kk) {
      bf16x8 af = W1f[(mf * 4 + kk) * 64 + lane];
      acc = __builtin_amdgcn_mfma_f32_16x16x32_bf16(af, bfr[kk], acc, 0, 0, 0);
    }
    if (node < NN) {
      ushort4 o;
      o.x = f2bu(acc[0]); o.y = f2bu(acc[1]); o.z = f2bu(acc[2]); o.w = f2bu(acc[3]);
      *(ushort4*)&h[(long long)node * 256 + mf * 16 + ch_base] = o;
    }
  }
}

// h2b[N,32](bf16) = x2b[N,256](bf16) @ W2.  2 channel-frags, 8 k-steps.
__global__ __launch_bounds__(256) void k_gemm2(const unsigned short* __restrict__ x2,
                                               const bf16x8* __restrict__ W2f,
                                               unsigned short* __restrict__ h) {
  __shared__ __align__(16) unsigned short xs[64 * 256];
  const int tid = threadIdx.x;
  const int n0 = blockIdx.x * 64;
  for (int j = tid; j < 2048; j += 256) {       // straight bf16 copy
    int r = j >> 5;
    int c8 = (j & 31) << 3;
    long long row = n0 + r; if (row >= NN) row = NN - 1;
    *(uint4*)&xs[r * 256 + c8] = *(const uint4*)(x2 + row * 256 + c8);
  }
  __syncthreads();
  const int w = tid >> 6, lane = tid & 63;
  const int nloc = w * 16 + (lane & 15);
  const int node = n0 + nloc;
  bf16x8 bfr[8];
  #pragma unroll
  for (int kk = 0; kk < 8; ++kk)
    bfr[kk] = *(const bf16x8*)&xs[nloc * 256 + kk * 32 + (lane >> 4) * 8];
  const int ch_base = (lane >> 4) * 4;
  #pragma unroll
  for (int mf = 0; mf < 2; ++mf) {
    f32x4 acc = {0.f, 0.f, 0.f, 0.f};
    #pragma unroll
    for (int kk = 0; kk < 8; ++kk) {
      bf16x8 af = W2f[(mf * 8 + kk) * 64 + lane];
      acc = __builtin_amdgcn_mfma_f32_16x16x32_bf16(af, bfr[kk], acc, 0, 0, 0);
    }
    if (node < NN) {
      ushort4 o;
      o.x = f2bu(acc[0]); o.y = f2bu(acc[1]); o.z = f2bu(acc[2]); o.w = f2bu(acc[3]);
      *(ushort4*)&h[(long long)node * 32 + mf * 16 + ch_base] = o;
    }
  }
}

// h3b[N,40](bf16) = x3b[N,32](bf16) @ W3.  3 channel-frags (padded), 1 k-step.
__global__ __launch_bounds__(256) void k_gemm3(const unsigned short* __restrict__ x3,
                                               const bf16x8* __restrict__ W3f,
                                               unsigned short* __restrict__ h) {
  __shared__ __align__(16) unsigned short xs[64 * 32];
  const int tid = threadIdx.x;
  const int n0 = blockIdx.x * 64;
  {
    // FIX(r3): stage ALL 32 columns of each row (was covering only cols 0..15).
    // 64 rows x 4 chunks of 8 ushorts = 256 uint4 loads, one per thread.
    int r = tid >> 2;
    int c8 = (tid & 3) << 3;
    long long row = n0 + r; if (row >= NN) row = NN - 1;
    *(uint4*)&xs[r * 32 + c8] = *(const uint4*)(x3 + row * 32 + c8);
  }
  __syncthreads();
  const int w = tid >> 6, lane = tid & 63;
  const int nloc = w * 16 + (lane & 15);
  const int node = n0 + nloc;
  bf16x8 bfr = *(const bf16x8*)&xs[nloc * 32 + (lane >> 4) * 8];
  const int ch_base = (lane >> 4) * 4;
  #pragma unroll
  for (int mf = 0; mf < 3; ++mf) {
    f32x4 acc = {0.f, 0.f, 0.f, 0.f};
    bf16x8 af = W3f[mf * 64 + lane];
    acc = __builtin_amdgcn_mfma_f32_16x16x32_bf16(af, bfr, acc, 0, 0, 0);
    int ch0 = mf * 16 + ch_base;
    if (node < NN && ch0 < 40) {
      ushort4 o;
      o.x = f2bu(acc[0]); o.y = f2bu(acc[1]); o.z = f2bu(acc[2]); o.w = f2bu(acc[3]);
      *(ushort4*)&h[(long long)node * 40 + ch0] = o;
    }
  }
}

// a_s/a_d layer 1 (H=8,C=32) from bf16 h. One block per node.
__global__ __launch_bounds__(256) void k_att1(const unsigned short* __restrict__ h,
                                              const float* __restrict__ as,
                                              const float* __restrict__ ad,
                                              float* __restrict__ a_s,
                                              float* __restrict__ a_d) {
  int n = blockIdx.x;
  int tid = threadIdx.x;            // head*32 + c
  float v = b2f(h[(long long)n * 256 + tid]);
  float p = v * as[tid];
  float q = v * ad[tid];
  #pragma unroll
  for (int off = 16; off; off >>= 1) {
    p += __shfl_down(p, off, 32);
    q += __shfl_down(q, off, 32);
  }
  if ((tid & 31) == 0) {
    int hd = tid >> 5;
    a_s[n * 8 + hd] = p;
    a_d[n * 8 + hd] = q;
  }
}

__global__ __launch_bounds__(256) void k_att2(const unsigned short* __restrict__ h,
                                              const float* __restrict__ as,
                                              const float* __restrict__ ad,
                                              float* __restrict__ a_s,
                                              float* __restrict__ a_d) {
  int n = blockIdx.x * 8 + (threadIdx.x >> 5);
  int c = threadIdx.x & 31;
  float v = b2f(h[(long long)n * 32 + c]);
  float p = v * as[c];
  float q = v * ad[c];
  #pragma unroll
  for (int off = 16; off; off >>= 1) {
    p += __shfl_down(p, off, 32);
    q += __shfl_down(q, off, 32);
  }
  if (c == 0) { a_s[n] = p; a_d[n] = q; }
}

__global__ __launch_bounds__(256) void k_att3(const unsigned short* __restrict__ h,
                                              const float* __restrict__ as,
                                              const float* __restrict__ ad,
                                              float* __restrict__ a_s,
                                              float* __restrict__ a_d) {
  int n = blockIdx.x * 256 + threadIdx.x;
  if (n >= NN) return;
  float p = 0.f, q = 0.f;
  #pragma unroll
  for (int c = 0; c < 40; ++c) {
    float v = b2f(h[(long long)n * 40 + c]);
    p += v * as[c];
    q += v * ad[c];
  }
  a_s[n] = p;
  a_d[n] = q;
}

// Layer-1 softmax+aggregate+bias+ELU -> bf16. One wave per node.
__global__ __launch_bounds__(256) void k_agg1(const int* __restrict__ rowptr,
                                              const int* __restrict__ csr,
                                              const float* __restrict__ a_s,
                                              const float* __restrict__ a_d,
                                              const unsigned short* __restrict__ h,
                                              const float* __restrict__ b,
                                              unsigned short* __restrict__ out) {
  const int node = blockIdx.x * 4 + (threadIdx.x >> 6);
  const int lane = threadIdx.x & 63;
  const int beg = rowptr[node], end = rowptr[node + 1];

  const int hd = lane & 7;
  const int eg = lane >> 3;
  const float adv = a_d[node * 8 + hd];
  float mx = -FNEG, sm = 0.f;
  for (int i = beg + eg; i < end; i += 8) {
    int s = csr[i];
    float v = lrelu(a_s[s * 8 + hd] + adv);
    float nm = fmaxf(mx, v);
    sm = sm * __expf(mx - nm) + __expf(v - nm);
    mx = nm;
  }
  #pragma unroll
  for (int off = 8; off < 64; off <<= 1) {
    float mo = __shfl_xor(mx, off);
    float so = __shfl_xor(sm, off);
    float nm = fmaxf(mx, mo);
    sm = sm * __expf(mx - nm) + so * __expf(mo - nm);
    mx = nm;
  }
  const int hd2 = lane >> 3;
  float m2 = __shfl(mx, hd2);
  float rden = 1.0f / __shfl(sm, hd2);
  const float adv2 = a_d[node * 8 + hd2];

  float4 acc = {0.f, 0.f, 0.f, 0.f};
  for (int i = beg; i < end; ++i) {
    int s = csr[i];
    float v = lrelu(a_s[s * 8 + hd2] + adv2);
    float alpha = __expf(v - m2) * rden;
    ushort4 hv = *(const ushort4*)(h + (long long)s * 256 + lane * 4);
    acc.x += alpha * b2f(hv.x);
    acc.y += alpha * b2f(hv.y);
    acc.z += alpha * b2f(hv.z);
    acc.w += alpha * b2f(hv.w);
  }
  float4 bv = *(const float4*)(b + lane * 4);
  acc.x += bv.x; acc.y += bv.y; acc.z += bv.z; acc.w += bv.w;
  acc.x = acc.x > 0.f ? acc.x : expm1f(acc.x);
  acc.y = acc.y > 0.f ? acc.y : expm1f(acc.y);
  acc.z = acc.z > 0.f ? acc.z : expm1f(acc.z);
  acc.w = acc.w > 0.f ? acc.w : expm1f(acc.w);
  ushort4 o;
  o.x = f2bu(acc.x); o.y = f2bu(acc.y); o.z = f2bu(acc.z); o.w = f2bu(acc.w);
  *(ushort4*)(out + (long long)node * 256 + lane * 4) = o;
}

// Layer-2 softmax+aggregate+bias+ELU -> bf16. Half-wave per node.
__global__ __launch_bounds__(256) void k_agg2(const int* __restrict__ rowptr,
                                              const int* __restrict__ csr,
                                              const float* __restrict__ a_s,
                                              const float* __restrict__ a_d,
                                              const unsigned short* __restrict__ h,
                                              const float* __restrict__ b,
                                              unsigned short* __restrict__ out) {
  const int node = blockIdx.x * 8 + (threadIdx.x >> 5);
  const int lane = threadIdx.x & 31;
  const int beg = rowptr[node], end = rowptr[node + 1];
  const float adv = a_d[node];

  float mx = -FNEG, sm = 0.f;
  for (int i = beg + lane; i < end; i += 32) {
    float v = lrelu(a_s[csr[i]] + adv);
    float nm = fmaxf(mx, v);
    sm = sm * __expf(mx - nm) + __expf(v - nm);
    mx = nm;
  }
  #pragma unroll
  for (int off = 1; off < 32; off <<= 1) {
    float mo = __shfl_xor(mx, off, 32);
    float so = __shfl_xor(sm, off, 32);
    float nm = fmaxf(mx, mo);
    sm = sm * __expf(mx - nm) + so * __expf(mo - nm);
    mx = nm;
  }
  float rden = 1.0f / sm;

  float acc = 0.f;
  for (int i = beg; i < end; ++i) {
    int s = csr[i];
    float alpha = __expf(lrelu(a_s[s] + adv) - mx) * rden;
    acc += alpha * b2f(h[(long long)s * 32 + lane]);
  }
  acc += b[lane];
  out[(long long)node * 32 + lane] = f2bu(acc > 0.f ? acc : expm1f(acc));
}

// Layer-3 softmax+aggregate + bias + log_softmax -> f32 out. Wave per node.
__global__ __launch_bounds__(256) void k_agg3(const int* __restrict__ rowptr,
                                              const int* __restrict__ csr,
                                              const float* __restrict__ a_s,
                                              const float* __restrict__ a_d,
                                              const unsigned short* __restrict__ h,
                                              const float* __restrict__ b,
                                              float* __restrict__ out) {
  const int node = blockIdx.x * 4 + (threadIdx.x >> 6);
  const int lane = threadIdx.x & 63;
  const int beg = rowptr[node], end = rowptr[node + 1];
  const float adv = a_d[node];

  float mx = -FNEG, sm = 0.f;
  for (int i = beg + lane; i < end; i += 64) {
    float v = lrelu(a_s[csr[i]] + adv);
    float nm = fmaxf(mx, v);
    sm = sm * __expf(mx - nm) + __expf(v - nm);
    mx = nm;
  }
  #pragma unroll
  for (int off = 1; off < 64; off <<= 1) {
    float mo = __shfl_xor(mx, off);
    float so = __shfl_xor(sm, off);
    float nm = fmaxf(mx, mo);
    sm = sm * __expf(mx - nm) + so * __expf(mo - nm);
    mx = nm;
  }
  float rden = 1.0f / sm;

  float acc = 0.f;
  for (int i = beg; i < end; ++i) {
    int s = csr[i];
    float alpha = __expf(lrelu(a_s[s] + adv) - mx) * rden;
    if (lane < 40) acc += alpha * b2f(h[(long long)s * 40 + lane]);
  }
  float v = (lane < 40) ? acc + b[lane] : -FNEG;
  float vmax = v;
  #pragma unroll
  for (int off = 1; off < 64; off <<= 1) vmax = fmaxf(vmax, __shfl_xor(vmax, off));
  float ex = (lane < 40) ? __expf(v - vmax) : 0.f;
  float es = ex;
  #pragma unroll
  for (int off = 1; off < 64; off <<= 1) es += __shfl_xor(es, off);
  float lse = vmax + __logf(es);
  if (lane < 40) out[(long long)node * 40 + lane] = v - lse;
}

extern "C" void kernel_launch(void* const* d_in, const int* in_sizes, int n_in,
                              void* d_out, int out_size, void* d_ws, size_t ws_size,
                              hipStream_t stream) {
  const float* x   = (const float*)d_in[0];
  const int*   eix = (const int*)d_in[1];
  const float* W1  = (const float*)d_in[2];
  const float* as1 = (const float*)d_in[3];
  const float* ad1 = (const float*)d_in[4];
  const float* b1  = (const float*)d_in[5];
  const float* W2  = (const float*)d_in[6];
  const float* as2 = (const float*)d_in[7];
  const float* ad2 = (const float*)d_in[8];
  const float* b2  = (const float*)d_in[9];
  const float* W3  = (const float*)d_in[10];
  const float* as3 = (const float*)d_in[11];
  const float* ad3 = (const float*)d_in[12];
  const float* b3  = (const float*)d_in[13];
  float* out = (float*)d_out;

  if (ws_size < WS_NEED) {
    k_sentinel<<<(out_size + 255) / 256, 256, 0, stream>>>(out, out_size);
    return;
  }

  char* ws = (char*)d_ws;
  int*    src    = (int*)(ws + SRC_OFF);
  int*    dst    = (int*)(ws + DST_OFF);
  int*    rowptr = (int*)(ws + RP_OFF);
  int*    cnt    = (int*)(ws + CNT_OFF);
  int*    csr    = (int*)(ws + CSR_OFF);
  unsigned short* W1f = (unsigned short*)(ws + W1F_OFF);
  unsigned short* W2f = (unsigned short*)(ws + W2F_OFF);
  unsigned short* W3f = (unsigned short*)(ws + W3F_OFF);
  int*    bsum   = (int*)(ws + SC_OFF);
  unsigned short* h1b  = (unsigned short*)(ws + H_OFF);
  unsigned short* h2b  = (unsigned short*)(ws + H_OFF);
  unsigned short* h3b  = (unsigned short*)(ws + H_OFF);
  unsigned short* agg1 = (unsigned short*)(ws + AGG_OFF);
  unsigned short* agg2 = (unsigned short*)(ws + AGG_OFF);
  float*  aS     = (float*)(ws + AS_OFF);
  float*  aD     = (float*)(ws + AD_OFF);

  // ---- CSR build + weight prep ----
  k_prep_w<<<21, 256, 0, stream>>>(W1, W2, W3, W1f, W2f, W3f);
  hipMemsetAsync(ws + CNT_OFF, 0, 400000, stream);
  k_prep_edges<<<(ET + 255) / 256, 256, 0, stream>>>(eix, src, dst, cnt);
  k_scan_a<<<NBSC, 1024, 0, stream>>>(cnt, rowptr, bsum);
  k_scan_b<<<1, 128, 0, stream>>>(bsum);
  k_scan_c<<<NBSC, 1024, 0, stream>>>(rowptr, bsum);
  hipMemsetAsync(ws + CNT_OFF, 0, 400000, stream);
  k_fill<<<(ET + 255) / 256, 256, 0, stream>>>(src, dst, rowptr, cnt, csr);

  // ---- layer 1: 128 -> 8x32 concat ----
  k_gemm1<<<(NN + 63) / 64, 256, 0, stream>>>(x, (const bf16x8*)W1f, h1b);
  k_att1<<<NN, 256, 0, stream>>>(h1b, as1, ad1, aS, aD);   // overwrites src/dst (dead)
  k_agg1<<<NN / 4, 256, 0, stream>>>(rowptr, csr, aS, aD, h1b, b1, agg1);

  // ---- layer 2: 256 -> 32 ----
  k_gemm2<<<(NN + 63) / 64, 256, 0, stream>>>(agg1, (const bf16x8*)W2f, h2b);
  k_att2<<<NN / 8, 256, 0, stream>>>(h2b, as2, ad2, aS, aD);
  k_agg2<<<NN / 8, 256, 0, stream>>>(rowptr, csr, aS, aD, h2b, b2, agg2);

  // ---- layer 3: 32 -> 40 ----
  k_gemm3<<<(NN + 63) / 64, 256, 0, stream>>>(agg2, (const bf16x8*)W3f, h3b);
  k_att3<<<(NN + 255) / 256, 256, 0, stream>>>(h3b, as3, ad3, aS, aD);
  k_agg3<<<NN / 4, 256, 0, stream>>>(rowptr, csr, aS, aD, h3b, b3, out);
}

// Round 5
// 646.240 us; speedup vs baseline: 10.8323x; 1.2634x over previous
//
#include <hip/hip_runtime.h>

#define NN 100000
#define NE 1600000
#define ET 1700000        // NE + NN self-loops
#define NEG 0.2f
#define FNEG 3.4e38f
#define NBSC 98           // scan blocks: ceil(NN/1024)

// ---------------- workspace layout (bytes) ----------------
#define SRC_OFF   0ULL
#define DST_OFF   6800000ULL
#define RP_OFF    13600000ULL         // rowptr (NN+1)*4
#define CNT_OFF   14000128ULL         // deg / fill cursor NN*4
#define CSR_OFF   14400128ULL         // ET*4
#define W1F_OFF   21200128ULL         // 65536  (16mf x 4kk x 64lane x 8 bf16)
#define W2F_OFF   21265664ULL         // 16384  (2mf x 8kk x 64 x 8)
#define W3F_OFF   21282048ULL         // 3072   (3mf x 1kk x 64 x 8)
#define SC_OFF    21285120ULL         // 1024 (block sums)
#define H_OFF     21286144ULL         // h1b 51.2MB (bf16); reused h2b/h3b
#define AGG_OFF   72486144ULL         // agg1b 51.2MB (bf16); reused agg2b
#define ALPH_OFF  123686144ULL        // alpha: ET*8*2 = 27.2MB (l1); ET*2 (l2,l3)
#define WS_NEED   150886144ULL
#define AS_OFF    SRC_OFF             // aS aliases src (dead after k_fill)
#define AD_OFF    DST_OFF

typedef short bf16x8 __attribute__((ext_vector_type(8)));
typedef float f32x4 __attribute__((ext_vector_type(4)));

__device__ __forceinline__ float lrelu(float x) { return x > 0.f ? x : NEG * x; }
__device__ __forceinline__ float b2f(unsigned short u) {
  return __uint_as_float(((unsigned)u) << 16);
}
__device__ __forceinline__ unsigned short f2bu(float f) {   // RNE f32->bf16
  unsigned u = __float_as_uint(f);
  return (unsigned short)((u + 0x7FFFu + ((u >> 16) & 1u)) >> 16);
}

__global__ __launch_bounds__(256) void k_sentinel(float* out, int n) {
  int i = blockIdx.x * 256 + threadIdx.x;
  if (i < n) out[i] = 12345.0f;
}

// Normalize edge_index (int32/int64 auto-detected) into int32 src/dst with
// self-loops appended; fused in-degree count.
__global__ __launch_bounds__(256) void k_prep_edges(const int* __restrict__ raw,
                                                    int* __restrict__ src,
                                                    int* __restrict__ dst,
                                                    int* __restrict__ deg) {
  bool is64 = true;
  #pragma unroll
  for (int i = 1; i < 32; i += 2) is64 = is64 && (raw[i] == 0);
  long long e = (long long)blockIdx.x * 256 + threadIdx.x;
  if (e >= ET) return;
  int s, d;
  if (e < NE) {
    if (is64) {
      const long long* r = (const long long*)raw;
      s = (int)r[e];
      d = (int)r[NE + e];
    } else {
      s = raw[e];
      d = raw[NE + e];
    }
  } else {
    s = d = (int)(e - NE);
  }
  src[e] = s;
  dst[e] = d;
  atomicAdd(&deg[d], 1);
}

// Block-level inclusive scan; rowptr[i+1] = block-local inclusive, bsum[b]=total.
__global__ __launch_bounds__(1024) void k_scan_a(const int* __restrict__ deg,
                                                 int* __restrict__ rowptr,
                                                 int* __restrict__ bsum) {
  __shared__ int wsum[16];
  const int lane = threadIdx.x & 63, wid = threadIdx.x >> 6;
  int i = blockIdx.x * 1024 + threadIdx.x;
  int x = (i < NN) ? deg[i] : 0;
  int inc = x;
  #pragma unroll
  for (int off = 1; off < 64; off <<= 1) {
    int t = __shfl_up(inc, off);
    if (lane >= off) inc += t;
  }
  if (lane == 63) wsum[wid] = inc;
  __syncthreads();
  if (wid == 0) {
    int w = (lane < 16) ? wsum[lane] : 0;
    #pragma unroll
    for (int off = 1; off < 16; off <<= 1) {
      int t = __shfl_up(w, off);
      if (lane >= off) w += t;
    }
    if (lane < 16) wsum[lane] = w;
  }
  __syncthreads();
  int base = wid ? wsum[wid - 1] : 0;
  if (i < NN) rowptr[i + 1] = base + inc;
  if (threadIdx.x == 1023) bsum[blockIdx.x] = base + inc;
}

// Exclusive scan of NBSC block sums (in place).
__global__ __launch_bounds__(128) void k_scan_b(int* __restrict__ bsum) {
  __shared__ int w0tot;
  int tid = threadIdx.x;
  int v = (tid < NBSC) ? bsum[tid] : 0;
  int inc = v;
  #pragma unroll
  for (int off = 1; off < 64; off <<= 1) {
    int t = __shfl_up(inc, off);
    if ((tid & 63) >= off) inc += t;
  }
  if (tid == 63) w0tot = inc;
  __syncthreads();
  if (tid >= 64) inc += w0tot;
  if (tid < NBSC) bsum[tid] = inc - v;
}

__global__ __launch_bounds__(1024) void k_scan_c(int* __restrict__ rowptr,
                                                 const int* __restrict__ bsum) {
  int i = blockIdx.x * 1024 + threadIdx.x;
  if (i < NN) rowptr[i + 1] += bsum[blockIdx.x];
  if (i == 0) rowptr[0] = 0;
}

__global__ __launch_bounds__(256) void k_fill(const int* __restrict__ src,
                                              const int* __restrict__ dst,
                                              const int* __restrict__ rowptr,
                                              int* __restrict__ cnt,
                                              int* __restrict__ csr) {
  long long e = (long long)blockIdx.x * 256 + threadIdx.x;
  if (e >= ET) return;
  int d = dst[e];
  int p = atomicAdd(&cnt[d], 1);
  csr[rowptr[d] + p] = src[e];
}

// Pre-arrange W1/W2/W3 (f32) into MFMA A-fragment order as bf16.
// A-frag convention: row(channel) = lane&15, k = (lane>>4)*8 + j.
__global__ __launch_bounds__(256) void k_prep_w(const float* __restrict__ W1,
                                                const float* __restrict__ W2,
                                                const float* __restrict__ W3,
                                                unsigned short* __restrict__ W1f,
                                                unsigned short* __restrict__ W2f,
                                                unsigned short* __restrict__ W3f) {
  int idx = blockIdx.x * 256 + threadIdx.x;
  if (idx < 4096) {                       // W1: 16 mf x 4 kk
    int fg = idx >> 6, lane = idx & 63;
    int mf = fg >> 2, kk = fg & 3;
    int c = mf * 16 + (lane & 15), k0 = kk * 32 + (lane >> 4) * 8;
    unsigned short* o = W1f + idx * 8;
    #pragma unroll
    for (int j = 0; j < 8; ++j) o[j] = f2bu(W1[(k0 + j) * 256 + c]);
  } else if (idx < 5120) {                // W2: 2 mf x 8 kk
    int t = idx - 4096;
    int fg = t >> 6, lane = t & 63;
    int mf = fg >> 3, kk = fg & 7;
    int c = mf * 16 + (lane & 15), k0 = kk * 32 + (lane >> 4) * 8;
    unsigned short* o = W2f + t * 8;
    #pragma unroll
    for (int j = 0; j < 8; ++j) o[j] = f2bu(W2[(k0 + j) * 32 + c]);
  } else if (idx < 5312) {                // W3: 3 mf x 1 kk (pad ch>=40 with 0)
    int t = idx - 5120;
    int mf = t >> 6, lane = t & 63;
    int c = mf * 16 + (lane & 15), k0 = (lane >> 4) * 8;
    unsigned short* o = W3f + t * 8;
    #pragma unroll
    for (int j = 0; j < 8; ++j) o[j] = (c < 40) ? f2bu(W3[(k0 + j) * 40 + c]) : 0;
  }
}

// h1b[N,256](bf16) = x[N,128] @ W1, fused a_s/a_d epilogue (kills k_att1).
// 64 nodes/block (4 waves x 16), K=128 (4 k-steps), 16 channel-frags.
__global__ __launch_bounds__(256) void k_gemm1(const float* __restrict__ x,
                                               const bf16x8* __restrict__ W1f,
                                               const float* __restrict__ as1,
                                               const float* __restrict__ ad1,
                                               unsigned short* __restrict__ h,
                                               float* __restrict__ a_s,
                                               float* __restrict__ a_d) {
  __shared__ __align__(16) unsigned short xs[64 * 128];
  __shared__ float asL[256], adL[256];
  const int tid = threadIdx.x;
  const int n0 = blockIdx.x * 64;
  asL[tid] = as1[tid];
  adL[tid] = ad1[tid];
  for (int j = tid; j < 2048; j += 256) {       // stage x -> bf16 LDS
    int r = j >> 5;
    int c4 = (j & 31) << 2;
    long long row = n0 + r; if (row >= NN) row = NN - 1;
    float4 v = *(const float4*)(x + row * 128 + c4);
    unsigned short* p = &xs[r * 128 + c4];
    p[0] = f2bu(v.x); p[1] = f2bu(v.y); p[2] = f2bu(v.z); p[3] = f2bu(v.w);
  }
  __syncthreads();
  const int w = tid >> 6, lane = tid & 63;
  const int nloc = w * 16 + (lane & 15);
  const int node = n0 + nloc;
  bf16x8 bfr[4];
  #pragma unroll
  for (int kk = 0; kk < 4; ++kk)
    bfr[kk] = *(const bf16x8*)&xs[nloc * 128 + kk * 32 + (lane >> 4) * 8];
  const int ch_base = (lane >> 4) * 4;
  float sA[8] = {}, sD[8] = {};
  #pragma unroll
  for (int mf = 0; mf < 16; ++mf) {
    f32x4 acc = {0.f, 0.f, 0.f, 0.f};
    #pragma unroll
    for (int kk = 0; kk < 4; ++kk) {
      bf16x8 af = W1f[(mf * 4 + kk) * 64 + lane];
      acc = __builtin_amdgcn_mfma_f32_16x16x32_bf16(af, bfr[kk], acc, 0, 0, 0);
    }
    // attention partial dots (channels mf*16+ch_base .. +3)
    const float* av = &asL[mf * 16 + ch_base];
    const float* dv = &adL[mf * 16 + ch_base];
    float ps = acc[0] * av[0] + acc[1] * av[1] + acc[2] * av[2] + acc[3] * av[3];
    float pd = acc[0] * dv[0] + acc[1] * dv[1] + acc[2] * dv[2] + acc[3] * dv[3];
    ps += __shfl_xor(ps, 16); ps += __shfl_xor(ps, 32);
    pd += __shfl_xor(pd, 16); pd += __shfl_xor(pd, 32);
    sA[mf >> 1] += ps; sD[mf >> 1] += pd;
    if (node < NN) {
      ushort4 o;
      o.x = f2bu(acc[0]); o.y = f2bu(acc[1]); o.z = f2bu(acc[2]); o.w = f2bu(acc[3]);
      *(ushort4*)&h[(long long)node * 256 + mf * 16 + ch_base] = o;
    }
  }
  if (lane < 16 && node < NN) {
    #pragma unroll
    for (int hd = 0; hd < 8; ++hd) {
      a_s[node * 8 + hd] = sA[hd];
      a_d[node * 8 + hd] = sD[hd];
    }
  }
}

// h2b[N,32](bf16) = x2b[N,256](bf16) @ W2, fused a_s/a_d (H=1).
__global__ __launch_bounds__(256) void k_gemm2(const unsigned short* __restrict__ x2,
                                               const bf16x8* __restrict__ W2f,
                                               const float* __restrict__ as2,
                                               const float* __restrict__ ad2,
                                               unsigned short* __restrict__ h,
                                               float* __restrict__ a_s,
                                               float* __restrict__ a_d) {
  __shared__ __align__(16) unsigned short xs[64 * 256];
  __shared__ float asL[32], adL[32];
  const int tid = threadIdx.x;
  const int n0 = blockIdx.x * 64;
  if (tid < 32) { asL[tid] = as2[tid]; adL[tid] = ad2[tid]; }
  for (int j = tid; j < 2048; j += 256) {
    int r = j >> 5;
    int c8 = (j & 31) << 3;
    long long row = n0 + r; if (row >= NN) row = NN - 1;
    *(uint4*)&xs[r * 256 + c8] = *(const uint4*)(x2 + row * 256 + c8);
  }
  __syncthreads();
  const int w = tid >> 6, lane = tid & 63;
  const int nloc = w * 16 + (lane & 15);
  const int node = n0 + nloc;
  bf16x8 bfr[8];
  #pragma unroll
  for (int kk = 0; kk < 8; ++kk)
    bfr[kk] = *(const bf16x8*)&xs[nloc * 256 + kk * 32 + (lane >> 4) * 8];
  const int ch_base = (lane >> 4) * 4;
  float sA = 0.f, sD = 0.f;
  #pragma unroll
  for (int mf = 0; mf < 2; ++mf) {
    f32x4 acc = {0.f, 0.f, 0.f, 0.f};
    #pragma unroll
    for (int kk = 0; kk < 8; ++kk) {
      bf16x8 af = W2f[(mf * 8 + kk) * 64 + lane];
      acc = __builtin_amdgcn_mfma_f32_16x16x32_bf16(af, bfr[kk], acc, 0, 0, 0);
    }
    const float* av = &asL[mf * 16 + ch_base];
    const float* dv = &adL[mf * 16 + ch_base];
    float ps = acc[0] * av[0] + acc[1] * av[1] + acc[2] * av[2] + acc[3] * av[3];
    float pd = acc[0] * dv[0] + acc[1] * dv[1] + acc[2] * dv[2] + acc[3] * dv[3];
    ps += __shfl_xor(ps, 16); ps += __shfl_xor(ps, 32);
    pd += __shfl_xor(pd, 16); pd += __shfl_xor(pd, 32);
    sA += ps; sD += pd;
    if (node < NN) {
      ushort4 o;
      o.x = f2bu(acc[0]); o.y = f2bu(acc[1]); o.z = f2bu(acc[2]); o.w = f2bu(acc[3]);
      *(ushort4*)&h[(long long)node * 32 + mf * 16 + ch_base] = o;
    }
  }
  if (lane < 16 && node < NN) { a_s[node] = sA; a_d[node] = sD; }
}

// h3b[N,40](bf16) = x3b[N,32](bf16) @ W3, fused a_s/a_d (H=1, 40ch padded).
__global__ __launch_bounds__(256) void k_gemm3(const unsigned short* __restrict__ x3,
                                               const bf16x8* __restrict__ W3f,
                                               const float* __restrict__ as3,
                                               const float* __restrict__ ad3,
                                               unsigned short* __restrict__ h,
                                               float* __restrict__ a_s,
                                               float* __restrict__ a_d) {
  __shared__ __align__(16) unsigned short xs[64 * 32];
  __shared__ float asL[48], adL[48];
  const int tid = threadIdx.x;
  const int n0 = blockIdx.x * 64;
  if (tid < 48) {
    asL[tid] = (tid < 40) ? as3[tid] : 0.f;
    adL[tid] = (tid < 40) ? ad3[tid] : 0.f;
  }
  {
    int r = tid >> 2;
    int c8 = (tid & 3) << 3;
    long long row = n0 + r; if (row >= NN) row = NN - 1;
    *(uint4*)&xs[r * 32 + c8] = *(const uint4*)(x3 + row * 32 + c8);
  }
  __syncthreads();
  const int w = tid >> 6, lane = tid & 63;
  const int nloc = w * 16 + (lane & 15);
  const int node = n0 + nloc;
  bf16x8 bfr = *(const bf16x8*)&xs[nloc * 32 + (lane >> 4) * 8];
  const int ch_base = (lane >> 4) * 4;
  float sA = 0.f, sD = 0.f;
  #pragma unroll
  for (int mf = 0; mf < 3; ++mf) {
    f32x4 acc = {0.f, 0.f, 0.f, 0.f};
    bf16x8 af = W3f[mf * 64 + lane];
    acc = __builtin_amdgcn_mfma_f32_16x16x32_bf16(af, bfr, acc, 0, 0, 0);
    const float* av = &asL[mf * 16 + ch_base];
    const float* dv = &adL[mf * 16 + ch_base];
    float ps = acc[0] * av[0] + acc[1] * av[1] + acc[2] * av[2] + acc[3] * av[3];
    float pd = acc[0] * dv[0] + acc[1] * dv[1] + acc[2] * dv[2] + acc[3] * dv[3];
    ps += __shfl_xor(ps, 16); ps += __shfl_xor(ps, 32);
    pd += __shfl_xor(pd, 16); pd += __shfl_xor(pd, 32);
    sA += ps; sD += pd;
    int ch0 = mf * 16 + ch_base;
    if (node < NN && ch0 < 40) {
      ushort4 o;
      o.x = f2bu(acc[0]); o.y = f2bu(acc[1]); o.z = f2bu(acc[2]); o.w = f2bu(acc[3]);
      *(ushort4*)&h[(long long)node * 40 + ch0] = o;
    }
  }
  if (lane < 16 && node < NN) { a_s[node] = sA; a_d[node] = sD; }
}

// Layer-1 softmax: per-node max/sum + write alpha[ET][8] bf16. Wave per node.
__global__ __launch_bounds__(256) void k_msalpha1(const int* __restrict__ rowptr,
                                                  const int* __restrict__ csr,
                                                  const float* __restrict__ a_s,
                                                  const float* __restrict__ a_d,
                                                  unsigned short* __restrict__ alph) {
  const int node = blockIdx.x * 4 + (threadIdx.x >> 6);
  const int lane = threadIdx.x & 63;
  const int beg = rowptr[node], end = rowptr[node + 1];
  const int hd = lane & 7;
  const int eg = lane >> 3;
  const float adv = a_d[node * 8 + hd];
  float mx = -FNEG, sm = 0.f;
  for (int i = beg + eg; i < end; i += 8) {
    int s = csr[i];
    float v = lrelu(a_s[s * 8 + hd] + adv);
    float nm = fmaxf(mx, v);
    sm = sm * __expf(mx - nm) + __expf(v - nm);
    mx = nm;
  }
  #pragma unroll
  for (int off = 8; off < 64; off <<= 1) {
    float mo = __shfl_xor(mx, off);
    float so = __shfl_xor(sm, off);
    float nm = fmaxf(mx, mo);
    sm = sm * __expf(mx - nm) + so * __expf(mo - nm);
    mx = nm;
  }
  float rden = 1.0f / sm;
  for (int i = beg + eg; i < end; i += 8) {
    int s = csr[i];
    float v = lrelu(a_s[s * 8 + hd] + adv);
    alph[i * 8 + hd] = f2bu(__expf(v - mx) * rden);
  }
}

// Layer-1 pure gather + bias + ELU -> bf16. Wave per node, 2-way unroll.
__global__ __launch_bounds__(256) void k_gather1(const int* __restrict__ rowptr,
                                                 const int* __restrict__ csr,
                                                 const unsigned short* __restrict__ alph,
                                                 const unsigned short* __restrict__ h,
                                                 const float* __restrict__ b,
                                                 unsigned short* __restrict__ out) {
  const int node = blockIdx.x * 4 + (threadIdx.x >> 6);
  const int lane = threadIdx.x & 63;
  const int beg = rowptr[node], end = rowptr[node + 1];
  const int hd2 = lane >> 3;
  float4 acc = {0.f, 0.f, 0.f, 0.f};
  int i = beg;
  for (; i + 2 <= end; i += 2) {
    int s0 = csr[i], s1 = csr[i + 1];
    float a0 = b2f(alph[i * 8 + hd2]);
    float a1 = b2f(alph[(i + 1) * 8 + hd2]);
    ushort4 h0 = *(const ushort4*)(h + (long long)s0 * 256 + lane * 4);
    ushort4 h1 = *(const ushort4*)(h + (long long)s1 * 256 + lane * 4);
    acc.x += a0 * b2f(h0.x) + a1 * b2f(h1.x);
    acc.y += a0 * b2f(h0.y) + a1 * b2f(h1.y);
    acc.z += a0 * b2f(h0.z) + a1 * b2f(h1.z);
    acc.w += a0 * b2f(h0.w) + a1 * b2f(h1.w);
  }
  if (i < end) {
    int s0 = csr[i];
    float a0 = b2f(alph[i * 8 + hd2]);
    ushort4 h0 = *(const ushort4*)(h + (long long)s0 * 256 + lane * 4);
    acc.x += a0 * b2f(h0.x);
    acc.y += a0 * b2f(h0.y);
    acc.z += a0 * b2f(h0.z);
    acc.w += a0 * b2f(h0.w);
  }
  float4 bv = *(const float4*)(b + lane * 4);
  acc.x += bv.x; acc.y += bv.y; acc.z += bv.z; acc.w += bv.w;
  acc.x = acc.x > 0.f ? acc.x : expm1f(acc.x);
  acc.y = acc.y > 0.f ? acc.y : expm1f(acc.y);
  acc.z = acc.z > 0.f ? acc.z : expm1f(acc.z);
  acc.w = acc.w > 0.f ? acc.w : expm1f(acc.w);
  ushort4 o;
  o.x = f2bu(acc.x); o.y = f2bu(acc.y); o.z = f2bu(acc.z); o.w = f2bu(acc.w);
  *(ushort4*)(out + (long long)node * 256 + lane * 4) = o;
}

// Layer-2/3 softmax: max/sum + write alpha[ET] bf16. Half-wave per node.
__global__ __launch_bounds__(256) void k_msalpha2(const int* __restrict__ rowptr,
                                                  const int* __restrict__ csr,
                                                  const float* __restrict__ a_s,
                                                  const float* __restrict__ a_d,
                                                  unsigned short* __restrict__ alph) {
  const int node = blockIdx.x * 8 + (threadIdx.x >> 5);
  const int lane = threadIdx.x & 31;
  const int beg = rowptr[node], end = rowptr[node + 1];
  const float adv = a_d[node];
  float mx = -FNEG, sm = 0.f;
  for (int i = beg + lane; i < end; i += 32) {
    float v = lrelu(a_s[csr[i]] + adv);
    float nm = fmaxf(mx, v);
    sm = sm * __expf(mx - nm) + __expf(v - nm);
    mx = nm;
  }
  #pragma unroll
  for (int off = 1; off < 32; off <<= 1) {
    float mo = __shfl_xor(mx, off, 32);
    float so = __shfl_xor(sm, off, 32);
    float nm = fmaxf(mx, mo);
    sm = sm * __expf(mx - nm) + so * __expf(mo - nm);
    mx = nm;
  }
  float rden = 1.0f / sm;
  for (int i = beg + lane; i < end; i += 32) {
    float v = lrelu(a_s[csr[i]] + adv);
    alph[i] = f2bu(__expf(v - mx) * rden);
  }
}

// Layer-2 pure gather + bias + ELU -> bf16. Half-wave per node, 2-way unroll.
__global__ __launch_bounds__(256) void k_gather2(const int* __restrict__ rowptr,
                                                 const int* __restrict__ csr,
                                                 const unsigned short* __restrict__ alph,
                                                 const unsigned short* __restrict__ h,
                                                 const float* __restrict__ b,
                                                 unsigned short* __restrict__ out) {
  const int node = blockIdx.x * 8 + (threadIdx.x >> 5);
  const int lane = threadIdx.x & 31;
  const int beg = rowptr[node], end = rowptr[node + 1];
  float acc = 0.f;
  int i = beg;
  for (; i + 2 <= end; i += 2) {
    int s0 = csr[i], s1 = csr[i + 1];
    float a0 = b2f(alph[i]), a1 = b2f(alph[i + 1]);
    acc += a0 * b2f(h[(long long)s0 * 32 + lane]);
    acc += a1 * b2f(h[(long long)s1 * 32 + lane]);
  }
  if (i < end) {
    acc += b2f(alph[i]) * b2f(h[(long long)csr[i] * 32 + lane]);
  }
  acc += b[lane];
  out[(long long)node * 32 + lane] = f2bu(acc > 0.f ? acc : expm1f(acc));
}

// Layer-3 softmax: wave per node (strided 64).
__global__ __launch_bounds__(256) void k_msalpha3(const int* __restrict__ rowptr,
                                                  const int* __restrict__ csr,
                                                  const float* __restrict__ a_s,
                                                  const float* __restrict__ a_d,
                                                  unsigned short* __restrict__ alph) {
  const int node = blockIdx.x * 4 + (threadIdx.x >> 6);
  const int lane = threadIdx.x & 63;
  const int beg = rowptr[node], end = rowptr[node + 1];
  const float adv = a_d[node];
  float mx = -FNEG, sm = 0.f;
  for (int i = beg + lane; i < end; i += 64) {
    float v = lrelu(a_s[csr[i]] + adv);
    float nm = fmaxf(mx, v);
    sm = sm * __expf(mx - nm) + __expf(v - nm);
    mx = nm;
  }
  #pragma unroll
  for (int off = 1; off < 64; off <<= 1) {
    float mo = __shfl_xor(mx, off);
    float so = __shfl_xor(sm, off);
    float nm = fmaxf(mx, mo);
    sm = sm * __expf(mx - nm) + so * __expf(mo - nm);
    mx = nm;
  }
  float rden = 1.0f / sm;
  for (int i = beg + lane; i < end; i += 64) {
    float v = lrelu(a_s[csr[i]] + adv);
    alph[i] = f2bu(__expf(v - mx) * rden);
  }
}

// Layer-3 pure gather + bias + log_softmax -> f32 out. Wave per node.
__global__ __launch_bounds__(256) void k_gather3(const int* __restrict__ rowptr,
                                                 const int* __restrict__ csr,
                                                 const unsigned short* __restrict__ alph,
                                                 const unsigned short* __restrict__ h,
                                                 const float* __restrict__ b,
                                                 float* __restrict__ out) {
  const int node = blockIdx.x * 4 + (threadIdx.x >> 6);
  const int lane = threadIdx.x & 63;
  const int beg = rowptr[node], end = rowptr[node + 1];
  float acc = 0.f;
  int i = beg;
  for (; i + 2 <= end; i += 2) {
    int s0 = csr[i], s1 = csr[i + 1];
    float a0 = b2f(alph[i]), a1 = b2f(alph[i + 1]);
    if (lane < 40) {
      acc += a0 * b2f(h[(long long)s0 * 40 + lane]);
      acc += a1 * b2f(h[(long long)s1 * 40 + lane]);
    }
  }
  if (i < end && lane < 40) {
    acc += b2f(alph[i]) * b2f(h[(long long)csr[i] * 40 + lane]);
  }
  float v = (lane < 40) ? acc + b[lane] : -FNEG;
  float vmax = v;
  #pragma unroll
  for (int off = 1; off < 64; off <<= 1) vmax = fmaxf(vmax, __shfl_xor(vmax, off));
  float ex = (lane < 40) ? __expf(v - vmax) : 0.f;
  float es = ex;
  #pragma unroll
  for (int off = 1; off < 64; off <<= 1) es += __shfl_xor(es, off);
  float lse = vmax + __logf(es);
  if (lane < 40) out[(long long)node * 40 + lane] = v - lse;
}

extern "C" void kernel_launch(void* const* d_in, const int* in_sizes, int n_in,
                              void* d_out, int out_size, void* d_ws, size_t ws_size,
                              hipStream_t stream) {
  const float* x   = (const float*)d_in[0];
  const int*   eix = (const int*)d_in[1];
  const float* W1  = (const float*)d_in[2];
  const float* as1 = (const float*)d_in[3];
  const float* ad1 = (const float*)d_in[4];
  const float* b1  = (const float*)d_in[5];
  const float* W2  = (const float*)d_in[6];
  const float* as2 = (const float*)d_in[7];
  const float* ad2 = (const float*)d_in[8];
  const float* b2  = (const float*)d_in[9];
  const float* W3  = (const float*)d_in[10];
  const float* as3 = (const float*)d_in[11];
  const float* ad3 = (const float*)d_in[12];
  const float* b3  = (const float*)d_in[13];
  float* out = (float*)d_out;

  if (ws_size < WS_NEED) {
    k_sentinel<<<(out_size + 255) / 256, 256, 0, stream>>>(out, out_size);
    return;
  }

  char* ws = (char*)d_ws;
  int*    src    = (int*)(ws + SRC_OFF);
  int*    dst    = (int*)(ws + DST_OFF);
  int*    rowptr = (int*)(ws + RP_OFF);
  int*    cnt    = (int*)(ws + CNT_OFF);
  int*    csr    = (int*)(ws + CSR_OFF);
  unsigned short* W1f = (unsigned short*)(ws + W1F_OFF);
  unsigned short* W2f = (unsigned short*)(ws + W2F_OFF);
  unsigned short* W3f = (unsigned short*)(ws + W3F_OFF);
  int*    bsum   = (int*)(ws + SC_OFF);
  unsigned short* h1b  = (unsigned short*)(ws + H_OFF);
  unsigned short* h2b  = (unsigned short*)(ws + H_OFF);
  unsigned short* h3b  = (unsigned short*)(ws + H_OFF);
  unsigned short* agg1 = (unsigned short*)(ws + AGG_OFF);
  unsigned short* agg2 = (unsigned short*)(ws + AGG_OFF);
  unsigned short* alph = (unsigned short*)(ws + ALPH_OFF);
  float*  aS     = (float*)(ws + AS_OFF);
  float*  aD     = (float*)(ws + AD_OFF);

  // ---- CSR build + weight prep ----
  k_prep_w<<<21, 256, 0, stream>>>(W1, W2, W3, W1f, W2f, W3f);
  hipMemsetAsync(ws + CNT_OFF, 0, 400000, stream);
  k_prep_edges<<<(ET + 255) / 256, 256, 0, stream>>>(eix, src, dst, cnt);
  k_scan_a<<<NBSC, 1024, 0, stream>>>(cnt, rowptr, bsum);
  k_scan_b<<<1, 128, 0, stream>>>(bsum);
  k_scan_c<<<NBSC, 1024, 0, stream>>>(rowptr, bsum);
  hipMemsetAsync(ws + CNT_OFF, 0, 400000, stream);
  k_fill<<<(ET + 255) / 256, 256, 0, stream>>>(src, dst, rowptr, cnt, csr);

  // ---- layer 1: 128 -> 8x32 concat ----
  k_gemm1<<<(NN + 63) / 64, 256, 0, stream>>>(x, (const bf16x8*)W1f, as1, ad1,
                                              h1b, aS, aD);  // aS/aD over src/dst (dead)
  k_msalpha1<<<NN / 4, 256, 0, stream>>>(rowptr, csr, aS, aD, alph);
  k_gather1<<<NN / 4, 256, 0, stream>>>(rowptr, csr, alph, h1b, b1, agg1);

  // ---- layer 2: 256 -> 32 ----
  k_gemm2<<<(NN + 63) / 64, 256, 0, stream>>>(agg1, (const bf16x8*)W2f, as2, ad2,
                                              h2b, aS, aD);
  k_msalpha2<<<NN / 8, 256, 0, stream>>>(rowptr, csr, aS, aD, alph);
  k_gather2<<<NN / 8, 256, 0, stream>>>(rowptr, csr, alph, h2b, b2, agg2);

  // ---- layer 3: 32 -> 40 ----
  k_gemm3<<<(NN + 63) / 64, 256, 0, stream>>>(agg2, (const bf16x8*)W3f, as3, ad3,
                                              h3b, aS, aD);
  k_msalpha3<<<NN / 4, 256, 0, stream>>>(rowptr, csr, aS, aD, alph);
  k_gather3<<<NN / 4, 256, 0, stream>>>(rowptr, csr, alph, h3b, b3, out);
}